// Round 7
// baseline (142.516 us; speedup 1.0000x reference)
//
#include <hip/hip_runtime.h>
#include <math.h>

// Problem constants (from reference)
#define NA 3
#define NC 80
#define CH 85              // NC+5
#define NB 16
#define HH 52
#define WW 52
#define HW 2704            // HH*WW
#define HWF4 676           // HW/4
#define NT 256             // num targets
#define NCELLS (NB*NA*HW)  // 129792
#define NBMW 4056          // bitmap words = ceil(NCELLS/32)
#define STRIDE_F 8.0f      // 416/52
#define IGN_THR 0.5f

// R11 post-mortem: dense never beats ~1.4TB/s because NOTHING is in flight
// during transform/store (and __syncthreads drains vmcnt -> block tiles
// can't prefetch). fillBufferAligned does 6.3TB/s at 8% occupancy: BW =
// outstanding requests, not occupancy. R12: barrier-free WAVE pipeline.
// Wave-autonomous 16-px tiles (R9 math, verified) WITHOUT the VALU-heavy
// swizzle (plain [cell*86+c]: phase-1 writes = exact 2-way/bank = free
// per m136; phase-2 reads ~4-way, minor) PLUS cross-tile prefetch: issue
// tile k+1's 6 float4 loads before transforming tile k; no barriers
// anywhere in the dense path -> loads stay outstanding across the LDS
// round-trip (vmcnt/lgkmcnt independent). Shell from R11 (verified):
// single launch, prep block 0 (atomicExch tables), epilogue-after-dense
// on early blocks with a REDUCED tile share (2 vs 4-5 -> tail hidden),
// done-counter finalize.
#define NTPLANE 169        // 16-px tiles per (b,a) plane
#define NWTILES (NTPLANE*NB*NA)    // 8112 wave-tiles
#define S2 86              // LDS cell stride (words)
#define WLDS (16*S2)       // 1376 words per wave slice
#define NF4C 340           // output float4s per tile: 16*85/4

#define NEPIB 67           // epilogue-capable dense blocks (bids 1..67)
#define NEPIW (NEPIB*4)    // 268 epilogue waves, 2 tiles each
#define EPITILES (NEPIW*2) // 536 tiles owned by epilogue waves
#define NNORMB 445         // normal dense blocks (bids 68..512)
#define NNW (NNORMB*4)     // 1780 normal waves
#define NREM 456           // first 456 normal waves take a 5th tile
#define GRID (1 + NEPIB + NNORMB)  // 513

__device__ __forceinline__ float sigm(float z) { return 1.0f / (1.0f + expf(-z)); }
// -log(sigmoid(z)) = log1p(exp(-z));  -log(1-sigmoid(z)) = log1p(exp(z))
__device__ __forceinline__ float splus(float z) { return log1pf(expf(z)); }

// ws layout (bytes):
//   0    : float acc[16]  acc[0]=dense noobj, acc[1]=obj xywh+conf,
//                         acc[2]=cls, acc[3]=zero-cell correction
//   64   : int cnts[8]    {wcount, zcount, unused, done, prep_flag}
//   128  : int   wofs[256]
//   1152 : float wtx[256]
//   2176 : float wty[256]
//   3200 : float wtw[256]
//   4224 : float wth[256]
//   5248 : int   wlabel[256]
//   6272 : int   zofs[768]
// bytes [0,96) zeroed by a 96-B hipMemsetAsync (poisoned-ws safe).

__global__ __launch_bounds__(256) void yolo_one(
        const float* __restrict__ x, float* __restrict__ out,
        const float* __restrict__ target, float* acc, int* cnts,
        int* wofs, float* wtx, float* wty, float* wtw, float* wth,
        int* wlabel, int* zofs, float* __restrict__ out_total) {
    __shared__ float lds[4 * WLDS];    // 22016 B; prep aliases (17.3 KB)
    __shared__ int s_flag[2];
    int bid = blockIdx.x;
    int t = threadIdx.x;

    if (bid == 0) {
        // ---------------- prep block (R11-verified) ----------------
        unsigned int* bm = (unsigned int*)lds;          // [NBMW]
        int* s_keyobj = (int*)lds + NBMW;               // [256]
        int* s_cnt = (int*)lds + NBMW + NT;             // {wcnt, zcnt}
        if (t == 0) { s_cnt[0] = 0; s_cnt[1] = 0; }
        for (int i = t; i < NBMW; i += 256) bm[i] = 0u;

        const float awc[3] = {10.f, 16.f, 33.f};
        const float ahc[3] = {13.f, 30.f, 23.f};
        float timg = target[t*6 + 0];
        float gxc  = target[t*6 + 1] * (float)WW;
        float gyc  = target[t*6 + 2] * (float)HH;
        float gw   = target[t*6 + 3] * (float)WW;
        float gh   = target[t*6 + 4] * (float)HH;
        int label  = (int)target[t*6 + 5];

        float best_iou = -1.0f;
        int best = 0, ignbits = 0;
        for (int a = 0; a < 3; a++) {
            float inter = fminf(awc[a], gw) * fminf(ahc[a], gh);
            float iou = inter / (awc[a]*ahc[a] + 1e-16f + gw*gh - inter);
            if (iou > best_iou) { best_iou = iou; best = a; }  // first-max
            if (iou > IGN_THR) ignbits |= (1 << a);
        }
        int img = (int)timg;
        int gi = (int)gxc, gj = (int)gyc;
        int pixel = gj * WW + gi;
        int cellbase = img * (NA * HW) + pixel;
        int keyobj = cellbase + best * HW;
        s_keyobj[t] = keyobj;
        __syncthreads();

        // winner iff no later target maps to same cell (fixed-trip scan)
        bool dup = false;
        #pragma unroll 8
        for (int m = 0; m < NT; m++) {
            int k = s_keyobj[m];
            dup = dup || (m > t && k == keyobj);
        }
        int sink = 0;
        if (!dup) {
            int p = atomicAdd(&s_cnt[0], 1);
            // publish winner table via device-coherent atomics (no fence)
            sink ^= atomicExch(&wofs[p], (img * NA + best) * (CH * HW) + pixel);
            sink ^= __float_as_int(atomicExch(&wtx[p], gxc - floorf(gxc)));
            sink ^= __float_as_int(atomicExch(&wty[p], gyc - floorf(gyc)));
            sink ^= __float_as_int(atomicExch(&wtw[p], logf(gw / awc[best] + 1e-16f)));
            sink ^= __float_as_int(atomicExch(&wth[p], logf(gh / ahc[best] + 1e-16f)));
            sink ^= atomicExch(&wlabel[p], label);
        }
        // distinct zeroed-noobj cells via bitmap (first setter appends)
        for (int a = 0; a < 3; a++) {
            bool flag = (a == best) || ((ignbits >> a) & 1);
            if (flag) {
                int key = cellbase + a * HW;
                unsigned int bit = 1u << (key & 31);
                unsigned int old = atomicOr(&bm[key >> 5], bit);
                if (!(old & bit)) {
                    int p = atomicAdd(&s_cnt[1], 1);
                    sink ^= atomicExch(&zofs[p],
                                ((img * NA + a) * CH + 4) * HW + pixel);
                }
            }
        }
        asm volatile("" :: "v"(sink) : "memory");  // table exchanges done
        __syncthreads();
        if (t == 0) {
            int o0 = atomicExch(&cnts[0], s_cnt[0]);
            int o1 = atomicExch(&cnts[1], s_cnt[1]);
            asm volatile("" :: "v"(o0), "v"(o1) : "memory");
            int of = atomicExch(&cnts[4], 1);      // publish: prep ready
            asm volatile("" :: "v"(of) : "memory");
            int o = atomicAdd(&cnts[3], 1);
            if (o == GRID - 1) {
                float a0 = atomicAdd(&acc[0], 0.0f);
                float a1 = atomicAdd(&acc[1], 0.0f);
                float a2 = atomicAdd(&acc[2], 0.0f);
                float a3 = atomicAdd(&acc[3], 0.0f);
                float wc = (float)atomicAdd(&cnts[0], 0);
                float zc = (float)atomicAdd(&cnts[1], 0);
                float n_obj = fmaxf(wc, 1.0f);
                float n_noobj = fmaxf((float)NCELLS - zc, 1.0f);
                float cls_den = fmaxf(80.0f * wc, 1.0f);
                out_total[0] = a1 / n_obj + a2 / cls_den
                             + 0.5f * ((a0 - a3) / n_noobj);
            }
        }
        return;
    }

    // ================= dense: barrier-free per-wave pipeline =============
    int wave = t >> 6, lane = t & 63;
    int d = bid - 1;                    // 0..511
    float* wl = &lds[wave * WLDS];
    const float awc[3] = {10.f, 16.f, 33.f};
    const float ahc[3] = {13.f, 30.f, 23.f};

    int wt, tStride, tCount;
    if (d < NEPIB) {                    // epilogue waves: 2 tiles, early
        int ew = d * 4 + wave;          // 0..267
        wt = ew * 2; tStride = 1; tCount = 2;
    } else {                            // normal waves: 4-5 tiles
        int nw = (d - NEPIB) * 4 + wave;        // 0..1779
        wt = EPITILES + nw; tStride = NNW;
        tCount = 4 + (nw < NREM ? 1 : 0);
    }

    float noobj = 0.0f;
    float4 vc[6], vn[6];
    {   // prologue: load tile 0
        int ba_ = wt / NTPLANE, tp_ = wt - ba_ * NTPLANE;
        const float4* p_ = (const float4*)x + (size_t)ba_ * (CH * HWF4)
                                            + tp_ * 4 + (lane & 3);
        #pragma unroll
        for (int i = 0; i < 6; i++) {
            int c = i * 16 + (lane >> 2);
            if (c < CH) vc[i] = p_[(size_t)c * HWF4];
        }
    }
    for (int it = 0; it < tCount; it++) {
        bool hasnext = (it + 1 < tCount);
        int nwt = wt + tStride;
        if (hasnext) {                  // prefetch tile k+1 (stays in
            int ba_ = nwt / NTPLANE, tp_ = nwt - ba_ * NTPLANE;   // flight:
            const float4* p_ = (const float4*)x                   // no
                + (size_t)ba_ * (CH * HWF4) + tp_ * 4 + (lane & 3); // barriers)
            #pragma unroll
            for (int i = 0; i < 6; i++) {
                int c = i * 16 + (lane >> 2);
                if (c < CH) vn[i] = p_[(size_t)c * HWF4];
            }
        }
        int ba = wt / NTPLANE, tp = wt - ba * NTPLANE;
        int a = ba % NA;

        // Phase 1: transform vc -> per-wave LDS slice [cell*86 + c]
        #pragma unroll
        for (int i = 0; i < 6; i++) {
            int c = i * 16 + (lane >> 2);
            if (c < CH) {
                float r[4] = {vc[i].x, vc[i].y, vc[i].z, vc[i].w};
                #pragma unroll
                for (int k = 0; k < 4; k++) {
                    int cell = 4 * (lane & 3) + k;   // 0..15
                    float z = r[k], o;
                    if (c == 0) {
                        int gp = tp * 16 + cell;
                        int px = gp % WW;
                        o = (sigm(z) + (float)px) * STRIDE_F;
                    } else if (c == 1) {
                        int gp = tp * 16 + cell;
                        int py = gp / WW;
                        o = (sigm(z) + (float)py) * STRIDE_F;
                    } else if (c == 2) {
                        o = expf(z) * awc[a];
                    } else if (c == 3) {
                        o = expf(z) * ahc[a];
                    } else {
                        o = sigm(z);
                        if (c == 4) noobj += splus(z);
                    }
                    wl[cell * S2 + c] = o;
                }
            }
        }
        __builtin_amdgcn_wave_barrier();   // pin LDS write<->read ordering

        // Phase 2: 340 float4 stores, consecutive lanes -> consecutive f4s
        float4* o4 = (float4*)out + (size_t)ba * (HW * CH / 4) + tp * NF4C;
        #pragma unroll
        for (int i = 0; i < 6; i++) {
            int j = lane + i * 64;
            if (j < NF4C) {
                int flat = 4 * j;
                int ce = flat / CH;              // local cell 0..15
                int c0 = flat - ce * CH;
                float4 w;
                float* pw = &w.x;
                #pragma unroll
                for (int k = 0; k < 4; k++) {
                    int ch = c0 + k, cek = ce;
                    if (ch >= CH) { ch -= CH; cek += 1; }
                    pw[k] = wl[cek * S2 + ch];
                }
                o4[j] = w;
            }
        }
        __builtin_amdgcn_wave_barrier();   // next writes behind these reads

        if (hasnext) {
            #pragma unroll
            for (int i = 0; i < 6; i++) vc[i] = vn[i];
        }
        wt = nwt;
    }
    // per-wave noobj -> acc[0] (consumed for the done protocol)
    for (int off = 32; off > 0; off >>= 1)
        noobj += __shfl_down(noobj, off, 64);
    if (lane == 0) {
        float old = atomicAdd(&acc[0], noobj);
        asm volatile("" :: "v"(old) : "memory");
    }

    // ---------------- tail epilogue (blocks 1..67, after dense) ----------
    if (d < NEPIB) {
        // prep (~5us) vs our 2 dense tiles: poll succeeds almost instantly
        if (t == 0) {
            while (atomicAdd(&cnts[4], 0) == 0)
                __builtin_amdgcn_s_sleep(8);
            s_flag[0] = atomicAdd(&cnts[0], 0);        // wcount
            s_flag[1] = atomicAdd(&cnts[1], 0);        // zcount
        }
        __syncthreads();

        if (d < 64) {
            // ---- winner gather: one winner per 64-lane wave ----
            int w = d * 4 + wave;
            if (w < s_flag[0]) {
                int ofs = 0, label = 0;
                float ttx = 0.f, tty = 0.f, ttw = 0.f, tth = 0.f;
                if (lane == 0) {                   // coherent table reads
                    ofs   = atomicAdd(&wofs[w], 0);
                    label = atomicAdd(&wlabel[w], 0);
                    ttx = atomicAdd(&wtx[w], 0.0f);
                    tty = atomicAdd(&wty[w], 0.0f);
                    ttw = atomicAdd(&wtw[w], 0.0f);
                    tth = atomicAdd(&wth[w], 0.0f);
                }
                ofs   = __shfl(ofs, 0, 64);
                label = __shfl(label, 0, 64);
                const float* xp = x + ofs;
                float lcls;
                {   // class channels 0..63
                    float z = xp[(size_t)(5 + lane) * HW];
                    lcls = (lane == label) ? splus(-z) : splus(z);
                }
                if (lane < 16) {                   // class channels 64..79
                    int c = 64 + lane;
                    float z = xp[(size_t)(5 + c) * HW];
                    lcls += (c == label) ? splus(-z) : splus(z);
                }
                float other = 0.0f;
                if (lane == 0) {
                    float z0 = xp[0];
                    float z2 = xp[(size_t)2 * HW];
                    float z4 = xp[(size_t)4 * HW];
                    float cx = sigm(z0);
                    float dx = cx - ttx, dy = cx - tty;  // ref bug: cx for y
                    float dw = z2 - ttw, dh = z2 - tth;  // ref bug: pw for h
                    other = dx*dx + dy*dy + dw*dw + dh*dh + splus(-z4);
                }
                for (int off = 32; off > 0; off >>= 1)
                    lcls += __shfl_down(lcls, off, 64);
                if (lane == 0) {
                    float o1 = atomicAdd(&acc[1], other);
                    float o2 = atomicAdd(&acc[2], lcls);
                    asm volatile("" :: "v"(o1), "v"(o2) : "memory");
                }
            }
        } else {
            // ---- zero-cell noobj corrections (768 slots over 3 blocks) --
            int idx = (d - 64) * 256 + t;
            float vv = 0.0f;
            if (idx < s_flag[1]) {
                int z = atomicAdd(&zofs[idx], 0);      // coherent read
                vv = splus(x[z]);
            }
            for (int off = 32; off > 0; off >>= 1)
                vv += __shfl_down(vv, off, 64);
            if ((t & 63) == 0) {
                float o3 = atomicAdd(&acc[3], vv);
                asm volatile("" :: "v"(o3) : "memory");
            }
        }
    }

    // ---- done protocol (R10/R11-validated) ----
    __syncthreads();    // all waves' acc atomics consumed above
    if (t == 0) {
        int o = atomicAdd(&cnts[3], 1);
        if (o == GRID - 1) {
            float a0 = atomicAdd(&acc[0], 0.0f);   // coherent reads
            float a1 = atomicAdd(&acc[1], 0.0f);
            float a2 = atomicAdd(&acc[2], 0.0f);
            float a3 = atomicAdd(&acc[3], 0.0f);
            float wc = (float)atomicAdd(&cnts[0], 0);
            float zc = (float)atomicAdd(&cnts[1], 0);
            float n_obj = fmaxf(wc, 1.0f);
            float n_noobj = fmaxf((float)NCELLS - zc, 1.0f);
            float cls_den = fmaxf(80.0f * wc, 1.0f);
            out_total[0] = a1 / n_obj + a2 / cls_den
                         + 0.5f * ((a0 - a3) / n_noobj);
        }
    }
}

// ---------------------------------------------------------------------------
extern "C" void kernel_launch(void* const* d_in, const int* in_sizes, int n_in,
                              void* d_out, int out_size, void* d_ws, size_t ws_size,
                              hipStream_t stream) {
    (void)in_sizes; (void)n_in; (void)out_size; (void)ws_size;
    const float* x      = (const float*)d_in[0];
    const float* target = (const float*)d_in[1];
    float* out = (float*)d_out;

    char* ws = (char*)d_ws;
    float* acc      = (float*)(ws + 0);
    int*   cnts     = (int*)  (ws + 64);
    int*   wofs     = (int*)  (ws + 128);
    float* wtx      = (float*)(ws + 1152);
    float* wty      = (float*)(ws + 2176);
    float* wtw      = (float*)(ws + 3200);
    float* wth      = (float*)(ws + 4224);
    int*   wlabel   = (int*)  (ws + 5248);
    int*   zofs     = (int*)  (ws + 6272);

    // zero acc[16] + cnts[8] (workspace is poisoned between iterations)
    hipMemsetAsync(ws, 0, 96, stream);
    yolo_one<<<GRID, 256, 0, stream>>>(
        x, out, target, acc, cnts, wofs, wtx, wty, wtw, wth, wlabel, zofs,
        out + (size_t)NB * NA * HW * CH);
}